// Round 1
// baseline (298.710 us; speedup 1.0000x reference)
//
#include <hip/hip_runtime.h>
#include <stdint.h>

#define NEG_SLOPE 0.01f
#define HPG 32        // heads per block in k4_fused
#define TSTR 72       // padded T row stride (halfwords): 144B rotates banks by 4/head

typedef float f32x4 __attribute__((ext_vector_type(4)));
typedef short short8 __attribute__((ext_vector_type(8)));

__device__ inline short f2bf(float f) {
    union { float f; uint32_t u; } x; x.f = f;
    uint32_t r = x.u + 0x7FFF + ((x.u >> 16) & 1);   // RNE
    return (short)(r >> 16);
}
__device__ inline float bf2f(unsigned short u) {
    union { uint32_t u; float f; } x; x.u = ((uint32_t)u) << 16; return x.f;
}

// ---- K_init: zero head counters + ego fp32->bf16 + W^T frag pack ----------
__global__ void __launch_bounds__(256) k_init_bf(
        const float* __restrict__ ego, unsigned short* __restrict__ ego_bf,
        int NE8, int* head_cnt, int N,
        const float* __restrict__ rw, short* __restrict__ wfrag) {
    int i = blockIdx.x * 256 + threadIdx.x;
    if (i < N) head_cnt[i] = 0;
    if (blockIdx.x < 16) {                 // W^T frag pack: blocks 0..15
        int r = blockIdx.x;
        int tid = threadIdx.x;
        int lane = tid & 63;
        int c = lane & 15, q = lane >> 4;
        for (int ph = 0; ph < 2; ++ph) {
            int pair = (tid >> 6) + ph * 4;
            int t4 = pair >> 1, kh = pair & 1;
            int m = t4 * 16 + c;
            short8 f;
            for (int j = 0; j < 8; ++j) {
                int k = kh * 32 + q * 8 + j;
                f[j] = f2bf(rw[r * 4096 + k * 64 + m]);
            }
            *(short8*)(wfrag + ((size_t)((r * 4 + t4) * 2 + kh) * 64 + lane) * 8) = f;
        }
    }
    if (i >= NE8) return;
    const float4* p = (const float4*)ego + (size_t)i * 2;
    float4 a = p[0], b = p[1];
    short8 v;
    v[0] = f2bf(a.x); v[1] = f2bf(a.y); v[2] = f2bf(a.z); v[3] = f2bf(a.w);
    v[4] = f2bf(b.x); v[5] = f2bf(b.y); v[6] = f2bf(b.z); v[7] = f2bf(b.w);
    *(short8*)(ego_bf + (size_t)i * 8) = v;
}

// ---- K1: head histogram (rank no longer needed: k3 uses an atomic cursor) --
__global__ void __launch_bounds__(256) k1_hist(
        const int* __restrict__ head, int E, int* head_cnt) {
    int i = blockIdx.x * 256 + threadIdx.x;
    if (i < E) atomicAdd(&head_cnt[head[i]], 1);
}

// ---- K2a: per-block partial sums of head_cnt -------------------------------
__global__ void __launch_bounds__(512) k2a(const int* __restrict__ head_cnt,
                                           int N, int* partial) {
    __shared__ int sw[8];
    int i = blockIdx.x * 512 + threadIdx.x;
    int v = (i < N) ? head_cnt[i] : 0;
    for (int off = 32; off; off >>= 1) v += __shfl_down(v, off);
    int w = threadIdx.x >> 6, lane = threadIdx.x & 63;
    if (lane == 0) sw[w] = v;
    __syncthreads();
    if (threadIdx.x == 0) {
        int s = 0;
        for (int j = 0; j < 8; ++j) s += sw[j];
        partial[blockIdx.x] = s;
    }
}

// ---- K2c: scan -> head_off (+ cursor copy for k3) --------------------------
__global__ void __launch_bounds__(512) k2c(const int* __restrict__ head_cnt,
                                           int N, const int* __restrict__ partial,
                                           int* head_off, int* head_cur, int E) {
    __shared__ int s[512];
    __shared__ int bo_s;
    int t = threadIdx.x;
    if (t < 64) {
        int acc = 0;
        for (int i = t; i < blockIdx.x; i += 64) acc += partial[i];
        for (int off = 32; off; off >>= 1) acc += __shfl_down(acc, off);
        if (t == 0) bo_s = acc;
    }
    int i = blockIdx.x * 512 + t;
    int v = (i < N) ? head_cnt[i] : 0;
    s[t] = v;
    __syncthreads();
    for (int off = 1; off < 512; off <<= 1) {
        int x = (t >= off) ? s[t - off] : 0;
        __syncthreads();
        s[t] += x;
        __syncthreads();
    }
    if (i < N) {
        int e = s[t] - v + bo_s;
        head_off[i] = e;
        head_cur[i] = e;
    }
    if (i == 0) head_off[N] = E;
}

// ---- K3: head-sorted scatter of packed (tail | type<<20) records -----------
// 4B payload per edge; per-head ranges are contiguous so the scattered writes
// cluster into ~1 line per head (L2 byte-mask writeback merges cross-XCD).
__global__ void __launch_bounds__(256) k3_scatter(
        const int* __restrict__ head, const int* __restrict__ tail,
        const int* __restrict__ etype, int E, int* head_cur,
        int* __restrict__ recs2) {
    int i = blockIdx.x * 256 + threadIdx.x;
    if (i >= E) return;
    int h = head[i];
    int pos = atomicAdd(&head_cur[h], 1);
    recs2[pos] = tail[i] | (etype[i] << 20);   // N < 2^20, R <= 16
}

// ---- K4: fused transform + score + softmax + aggregate ---------------------
// Phase 1 (MFMA): block = 32 heads; wave w computes T[r][h] = W_r^T * head_row
// for its 2 types r = 2w,2w+1 and all 32 heads (head rows are CONTIGUOUS ->
// streamed, not gathered). Fragment math identical to the verified k4_scores
// path: acc[t4][i] = transformed[dim t4*16+q*4+i] of column head c.
// Phase 2: 16-lane quarter owns one head; per edge gather tail row ONCE,
// dot with LDS-resident T[type][head], exp, and accumulate weighted tail.
__global__ void __launch_bounds__(512, 4) k4_fused(
        const unsigned short* __restrict__ ego_bf,
        const short* __restrict__ wfrag,
        const int* __restrict__ recs2,
        const int* __restrict__ head_off,
        float* __restrict__ out, int N) {
    __shared__ unsigned short T[16 * HPG * TSTR];   // 73,728 B -> 2 blocks/CU
    int tid = threadIdx.x;
    int wave = tid >> 6;
    int lane = tid & 63;
    int c = lane & 15, q = lane >> 4;
    int hb = blockIdx.x * HPG;

    // ---------------- phase 1: per-wave 2 types x 32 heads ----------------
    for (int t = 0; t < 2; ++t) {
        int r = wave * 2 + t;
        const short* wp = wfrag + (size_t)r * 4096;
        short8 wf[4][2];
        #pragma unroll
        for (int t4 = 0; t4 < 4; ++t4)
            #pragma unroll
            for (int kh = 0; kh < 2; ++kh)
                wf[t4][kh] = *(const short8*)(wp + ((size_t)((t4 * 2 + kh) * 64 + lane)) * 8);
        #pragma unroll
        for (int hf = 0; hf < 2; ++hf) {
            int hrow = hb + hf * 16 + c;
            if (hrow >= N) hrow = N - 1;           // clamp; garbage T never read
            const unsigned short* hr = ego_bf + (size_t)hrow * 64;
            short8 b0 = *(const short8*)(hr + q * 8);
            short8 b1 = *(const short8*)(hr + 32 + q * 8);
            #pragma unroll
            for (int t4 = 0; t4 < 4; ++t4) {
                f32x4 a = {0.f, 0.f, 0.f, 0.f};
                a = __builtin_amdgcn_mfma_f32_16x16x32_bf16(wf[t4][0], b0, a, 0, 0, 0);
                a = __builtin_amdgcn_mfma_f32_16x16x32_bf16(wf[t4][1], b1, a, 0, 0, 0);
                ushort4 us;
                us.x = (unsigned short)f2bf(a[0]);
                us.y = (unsigned short)f2bf(a[1]);
                us.z = (unsigned short)f2bf(a[2]);
                us.w = (unsigned short)f2bf(a[3]);
                *(ushort4*)&T[(size_t)(r * HPG + hf * 16 + c) * TSTR + t4 * 16 + q * 4] = us;
            }
        }
    }
    __syncthreads();

    // ---------------- phase 2: quarter (wave,q) owns head hb + wave*4 + q --
    int hql = wave * 4 + q;
    int h = hb + hql;
    if (h >= N) return;
    int lq = c;                   // lane within quarter
    int g2 = lq >> 3, c8 = lq & 7;
    int qb = q * 16;
    int s0 = head_off[h], s1 = head_off[h + 1];
    int cnt = s1 - s0;
    float acc[8] = {0.f, 0.f, 0.f, 0.f, 0.f, 0.f, 0.f, 0.f};
    float den = 0.f;
    for (int base = s0; base < s1; base += 16) {
        int idx = base + lq;
        int recL = (idx < s1) ? recs2[idx] : 0;    // coalesced 64B per quarter
        int ng = s1 - base; if (ng > 16) ng = 16;
        short8 rows[8];
        int tys[8];
        #pragma unroll
        for (int sIt = 0; sIt < 8; ++sIt) {        // issue all gathers up front
            int rj = __shfl(recL, qb + sIt * 2 + g2);
            tys[sIt] = rj >> 20;
            if (sIt * 2 < ng) {
                int tn = rj & 0xFFFFF;
                rows[sIt] = *(const short8*)(ego_bf + (size_t)tn * 64 + c8 * 8);
            }
        }
        #pragma unroll
        for (int sIt = 0; sIt < 8; ++sIt) {
            if (sIt * 2 < ng) {
                short8 trw = *(const short8*)&T[(size_t)(tys[sIt] * HPG + hql) * TSTR + c8 * 8];
                float rf[8];
                float s = 0.f;
                #pragma unroll
                for (int k = 0; k < 8; ++k) {
                    rf[k] = bf2f((unsigned short)rows[sIt][k]);
                    s += rf[k] * bf2f((unsigned short)trw[k]);
                }
                s += __shfl_xor(s, 1);
                s += __shfl_xor(s, 2);
                s += __shfl_xor(s, 4);
                float lr = s > 0.f ? s : NEG_SLOPE * s;
                float w = (sIt * 2 + g2 < ng) ? __expf(lr) : 0.f;  // kill pad edge
                den += w;
                #pragma unroll
                for (int k = 0; k < 8; ++k) acc[k] += w * rf[k];
            }
        }
    }
    den += __shfl_xor(den, 8);                     // combine the 2 edge slots
    #pragma unroll
    for (int k = 0; k < 8; ++k) acc[k] += __shfl_xor(acc[k], 8);
    if (g2 == 0) {
        float sc = (cnt > 0) ? 1.f / (den * (float)cnt) : 0.f;
        float4 v0 = {acc[0] * sc, acc[1] * sc, acc[2] * sc, acc[3] * sc};
        float4 v1 = {acc[4] * sc, acc[5] * sc, acc[6] * sc, acc[7] * sc};
        float* op = out + (size_t)h * 64 + c8 * 8;
        *(float4*)op = v0;
        *(float4*)(op + 4) = v1;
    }
}

extern "C" void kernel_launch(void* const* d_in, const int* in_sizes, int n_in,
                              void* d_out, int out_size, void* d_ws, size_t ws_size,
                              hipStream_t stream) {
    const float* ego = (const float*)d_in[0];
    const float* rw  = (const float*)d_in[1];
    const int* eidx  = (const int*)d_in[2];
    const int* etyp  = (const int*)d_in[3];
    int N = in_sizes[0] / 64;
    int E = in_sizes[3];
    const int* head = eidx;
    const int* tail = eidx + E;
    float* out = (float*)d_out;

    char* ws = (char*)d_ws;
    size_t o = 0;
    auto take = [&](size_t bytes) -> char* {
        char* p = ws + o;
        o = (o + bytes + 255) & ~(size_t)255;
        return p;
    };
    int nb2 = (N + 511) / 512;
    unsigned short* ego_bf = (unsigned short*)take((size_t)N * 64 * 2);
    short* wfrag  = (short*)take(16 * 4096 * 2);
    int* recs2    = (int*)take((size_t)E * 4);
    int* head_cnt = (int*)take((size_t)N * 4);
    int* head_off = (int*)take((size_t)(N + 1) * 4);
    int* head_cur = (int*)take((size_t)N * 4);
    int* partial  = (int*)take((size_t)nb2 * 4);
    (void)ws_size; (void)n_in; (void)out_size;

    int NE8 = N * 8;
    k_init_bf<<<(NE8 + 255) / 256, 256, 0, stream>>>(ego, ego_bf, NE8,
                                                     head_cnt, N, rw, wfrag);
    k1_hist<<<(E + 255) / 256, 256, 0, stream>>>(head, E, head_cnt);
    k2a<<<nb2, 512, 0, stream>>>(head_cnt, N, partial);
    k2c<<<nb2, 512, 0, stream>>>(head_cnt, N, partial, head_off, head_cur, E);
    k3_scatter<<<(E + 255) / 256, 256, 0, stream>>>(head, tail, etyp, E,
                                                    head_cur, recs2);
    k4_fused<<<(N + HPG - 1) / HPG, 512, 0, stream>>>(ego_bf, wfrag, recs2,
                                                      head_off, out, N);
}

// Round 2
// 250.281 us; speedup vs baseline: 1.1935x; 1.1935x over previous
//
#include <hip/hip_runtime.h>
#include <stdint.h>

#define NEG_SLOPE 0.01f
#define HPG 32        // heads per block in k4_fused
#define TSTR 72       // padded T row stride (halfwords)
#define BSH 9         // head-bucket shift: bucket = head >> 9
#define NBMAX 256     // max buckets (N=100K -> 196)
#define CHUNKA 8192   // edges per k3a block

typedef float f32x4 __attribute__((ext_vector_type(4)));
typedef short short8 __attribute__((ext_vector_type(8)));

__device__ inline short f2bf(float f) {
    union { float f; uint32_t u; } x; x.f = f;
    uint32_t r = x.u + 0x7FFF + ((x.u >> 16) & 1);   // RNE
    return (short)(r >> 16);
}
__device__ inline float bf2f(unsigned short u) {
    union { uint32_t u; float f; } x; x.u = ((uint32_t)u) << 16; return x.f;
}

// ---- K_init: zero head counters + ego fp32->bf16 + W^T frag pack ----------
__global__ void __launch_bounds__(256) k_init_bf(
        const float* __restrict__ ego, unsigned short* __restrict__ ego_bf,
        int NE8, int* head_cnt, int N,
        const float* __restrict__ rw, short* __restrict__ wfrag) {
    int i = blockIdx.x * 256 + threadIdx.x;
    if (i < N) head_cnt[i] = 0;
    if (blockIdx.x < 16) {                 // W^T frag pack: blocks 0..15
        int r = blockIdx.x;
        int tid = threadIdx.x;
        int lane = tid & 63;
        int c = lane & 15, q = lane >> 4;
        for (int ph = 0; ph < 2; ++ph) {
            int pair = (tid >> 6) + ph * 4;
            int t4 = pair >> 1, kh = pair & 1;
            int m = t4 * 16 + c;
            short8 f;
            for (int j = 0; j < 8; ++j) {
                int k = kh * 32 + q * 8 + j;
                f[j] = f2bf(rw[r * 4096 + k * 64 + m]);
            }
            *(short8*)(wfrag + ((size_t)((r * 4 + t4) * 2 + kh) * 64 + lane) * 8) = f;
        }
    }
    if (i >= NE8) return;
    const float4* p = (const float4*)ego + (size_t)i * 2;
    float4 a = p[0], b = p[1];
    short8 v;
    v[0] = f2bf(a.x); v[1] = f2bf(a.y); v[2] = f2bf(a.z); v[3] = f2bf(a.w);
    v[4] = f2bf(b.x); v[5] = f2bf(b.y); v[6] = f2bf(b.z); v[7] = f2bf(b.w);
    *(short8*)(ego_bf + (size_t)i * 8) = v;
}

// ---- K1: head histogram; the atomic's return IS the rank (coalesced write) -
__global__ void __launch_bounds__(256) k1_hist(
        const int* __restrict__ head, int E, int* head_cnt,
        int* __restrict__ headrank) {
    int i = blockIdx.x * 256 + threadIdx.x;
    if (i < E) headrank[i] = atomicAdd(&head_cnt[head[i]], 1);
}

// ---- K2a: per-block partial sums of head_cnt -------------------------------
__global__ void __launch_bounds__(512) k2a(const int* __restrict__ head_cnt,
                                           int N, int* partial) {
    __shared__ int sw[8];
    int i = blockIdx.x * 512 + threadIdx.x;
    int v = (i < N) ? head_cnt[i] : 0;
    for (int off = 32; off; off >>= 1) v += __shfl_down(v, off);
    int w = threadIdx.x >> 6, lane = threadIdx.x & 63;
    if (lane == 0) sw[w] = v;
    __syncthreads();
    if (threadIdx.x == 0) {
        int s = 0;
        for (int j = 0; j < 8; ++j) s += sw[j];
        partial[blockIdx.x] = s;
    }
}

// ---- K2c: scan -> head_off; bucket cursors init for free -------------------
__global__ void __launch_bounds__(512) k2c(const int* __restrict__ head_cnt,
                                           int N, const int* __restrict__ partial,
                                           int* head_off, int* bucket_fill, int E) {
    __shared__ int s[512];
    __shared__ int bo_s;
    int t = threadIdx.x;
    if (t < 64) {
        int acc = 0;
        for (int i = t; i < blockIdx.x; i += 64) acc += partial[i];
        for (int off = 32; off; off >>= 1) acc += __shfl_down(acc, off);
        if (t == 0) bo_s = acc;
    }
    int i = blockIdx.x * 512 + t;
    int v = (i < N) ? head_cnt[i] : 0;
    s[t] = v;
    __syncthreads();
    for (int off = 1; off < 512; off <<= 1) {
        int x = (t >= off) ? s[t - off] : 0;
        __syncthreads();
        s[t] += x;
        __syncthreads();
    }
    if (i < N) {
        int e = s[t] - v + bo_s;
        head_off[i] = e;
        if ((i & ((1 << BSH) - 1)) == 0) bucket_fill[i >> BSH] = e;
    }
    if (i == 0) head_off[N] = E;
}

// ---- K3a: LDS-staged bin by head-bucket -> coalesced segment writes --------
// staging record: {pos, tail | type<<20 | bucket<<24}; bucket segments in the
// staging buffer coincide with the destination ranges (cursor init = head_off).
__global__ void __launch_bounds__(256) k3a_bin(
        const int* __restrict__ head, const int* __restrict__ tail,
        const int* __restrict__ etype, const int* __restrict__ headrank,
        const int* __restrict__ head_off, int E, int NB,
        int* bucket_fill, int2* __restrict__ staging) {
    __shared__ int lcnt[NBMAX], loff[NBMAX], lbase[NBMAX];
    __shared__ int2 lrec[CHUNKA];
    int t = threadIdx.x;
    for (int b = t; b < NBMAX; b += 256) lcnt[b] = 0;
    __syncthreads();
    long long base = (long long)blockIdx.x * CHUNKA;
    int myh[32], myrk[32];
    #pragma unroll
    for (int sI = 0; sI < 32; ++sI) {
        long long e = base + t + sI * 256;
        int h = -1, rk = 0;
        if (e < E) { h = head[e]; rk = atomicAdd(&lcnt[h >> BSH], 1); }
        myh[sI] = h; myrk[sI] = rk;
    }
    __syncthreads();
    for (int b = t; b < NB; b += 256)
        lbase[b] = atomicAdd(&bucket_fill[b], lcnt[b]);
    if (t < 64) {                          // exclusive scan of lcnt, one wave
        int c0 = lcnt[t * 4], c1 = lcnt[t * 4 + 1];
        int c2 = lcnt[t * 4 + 2], c3 = lcnt[t * 4 + 3];
        int cs = c0 + c1 + c2 + c3;
        int inc = cs;
        for (int off = 1; off < 64; off <<= 1) {
            int u = __shfl_up(inc, off);
            if (t >= off) inc += u;
        }
        int run = inc - cs;
        loff[t * 4] = run; run += c0;
        loff[t * 4 + 1] = run; run += c1;
        loff[t * 4 + 2] = run; run += c2;
        loff[t * 4 + 3] = run;
    }
    __syncthreads();
    #pragma unroll
    for (int sI = 0; sI < 32; ++sI) {
        long long e = base + t + sI * 256;
        if (e < E) {
            int h = myh[sI];
            int bk = h >> BSH;
            int2 rec;
            rec.x = head_off[h] + headrank[e];
            rec.y = tail[e] | (etype[e] << 20) | (bk << 24);
            lrec[loff[bk] + myrk[sI]] = rec;
        }
    }
    __syncthreads();
    int nvalid = (int)(((long long)E - base < CHUNKA) ? ((long long)E - base) : CHUNKA);
    for (int i = t; i < nvalid; i += 256) {
        int2 rec = lrec[i];
        int b = ((unsigned int)rec.y) >> 24;
        staging[lbase[b] + (i - loff[b])] = rec;       // coalesced segments
    }
}

// ---- K3b: window-local placement (dest range per bucket ~26KB, L2-hot) -----
__global__ void __launch_bounds__(256) k3b_place(
        const int2* __restrict__ staging, int E, int* __restrict__ recs2) {
    long long base = (long long)blockIdx.x * 2048;
    long long endl = base + 2048; if (endl > E) endl = E;
    int end = (int)endl;
    for (int i = (int)base + threadIdx.x; i < end; i += 256) {
        int2 rec = staging[i];
        recs2[rec.x] = rec.y & 0xFFFFFF;
    }
}

// ---- K4: fused transform + score + softmax + aggregate ---------------------
__global__ void __launch_bounds__(512, 4) k4_fused(
        const unsigned short* __restrict__ ego_bf,
        const short* __restrict__ wfrag,
        const int* __restrict__ recs2,
        const int* __restrict__ head_off,
        float* __restrict__ out, int N) {
    __shared__ unsigned short T[16 * HPG * TSTR];   // 73,728 B -> 2 blocks/CU
    int tid = threadIdx.x;
    int wave = tid >> 6;
    int lane = tid & 63;
    int c = lane & 15, q = lane >> 4;
    int hb = blockIdx.x * HPG;

    // ---------------- phase 1: per-wave 2 types x 32 heads ----------------
    for (int t = 0; t < 2; ++t) {
        int r = wave * 2 + t;
        const short* wp = wfrag + (size_t)r * 4096;
        short8 wf[4][2];
        #pragma unroll
        for (int t4 = 0; t4 < 4; ++t4)
            #pragma unroll
            for (int kh = 0; kh < 2; ++kh)
                wf[t4][kh] = *(const short8*)(wp + ((size_t)((t4 * 2 + kh) * 64 + lane)) * 8);
        #pragma unroll
        for (int hf = 0; hf < 2; ++hf) {
            int hrow = hb + hf * 16 + c;
            if (hrow >= N) hrow = N - 1;           // clamp; garbage T never read
            const unsigned short* hr = ego_bf + (size_t)hrow * 64;
            short8 b0 = *(const short8*)(hr + q * 8);
            short8 b1 = *(const short8*)(hr + 32 + q * 8);
            #pragma unroll
            for (int t4 = 0; t4 < 4; ++t4) {
                f32x4 a = {0.f, 0.f, 0.f, 0.f};
                a = __builtin_amdgcn_mfma_f32_16x16x32_bf16(wf[t4][0], b0, a, 0, 0, 0);
                a = __builtin_amdgcn_mfma_f32_16x16x32_bf16(wf[t4][1], b1, a, 0, 0, 0);
                ushort4 us;
                us.x = (unsigned short)f2bf(a[0]);
                us.y = (unsigned short)f2bf(a[1]);
                us.z = (unsigned short)f2bf(a[2]);
                us.w = (unsigned short)f2bf(a[3]);
                *(ushort4*)&T[(size_t)(r * HPG + hf * 16 + c) * TSTR + t4 * 16 + q * 4] = us;
            }
        }
    }
    __syncthreads();

    // ---------------- phase 2: quarter (wave,q) owns head hb + wave*4 + q --
    int hql = wave * 4 + q;
    int h = hb + hql;
    if (h >= N) return;
    int lq = c;                   // lane within quarter
    int g2 = lq >> 3, c8 = lq & 7;
    int qb = q * 16;
    int s0 = head_off[h], s1 = head_off[h + 1];
    int cnt = s1 - s0;
    float acc[8] = {0.f, 0.f, 0.f, 0.f, 0.f, 0.f, 0.f, 0.f};
    float den = 0.f;
    for (int base = s0; base < s1; base += 16) {
        int idx = base + lq;
        int recL = (idx < s1) ? recs2[idx] : 0;    // coalesced 64B per quarter
        int ng = s1 - base; if (ng > 16) ng = 16;
        short8 rows[8];
        int tys[8];
        #pragma unroll
        for (int sIt = 0; sIt < 8; ++sIt) {        // issue all gathers up front
            int rj = __shfl(recL, qb + sIt * 2 + g2);
            tys[sIt] = rj >> 20;
            if (sIt * 2 < ng) {
                int tn = rj & 0xFFFFF;
                rows[sIt] = *(const short8*)(ego_bf + (size_t)tn * 64 + c8 * 8);
            }
        }
        #pragma unroll
        for (int sIt = 0; sIt < 8; ++sIt) {
            if (sIt * 2 < ng) {
                short8 trw = *(const short8*)&T[(size_t)(tys[sIt] * HPG + hql) * TSTR + c8 * 8];
                float rf[8];
                float s = 0.f;
                #pragma unroll
                for (int k = 0; k < 8; ++k) {
                    rf[k] = bf2f((unsigned short)rows[sIt][k]);
                    s += rf[k] * bf2f((unsigned short)trw[k]);
                }
                s += __shfl_xor(s, 1);
                s += __shfl_xor(s, 2);
                s += __shfl_xor(s, 4);
                float lr = s > 0.f ? s : NEG_SLOPE * s;
                float w = (sIt * 2 + g2 < ng) ? __expf(lr) : 0.f;  // kill pad edge
                den += w;
                #pragma unroll
                for (int k = 0; k < 8; ++k) acc[k] += w * rf[k];
            }
        }
    }
    den += __shfl_xor(den, 8);                     // combine the 2 edge slots
    #pragma unroll
    for (int k = 0; k < 8; ++k) acc[k] += __shfl_xor(acc[k], 8);
    if (g2 == 0) {
        float sc = (cnt > 0) ? 1.f / (den * (float)cnt) : 0.f;
        float4 v0 = {acc[0] * sc, acc[1] * sc, acc[2] * sc, acc[3] * sc};
        float4 v1 = {acc[4] * sc, acc[5] * sc, acc[6] * sc, acc[7] * sc};
        float* op = out + (size_t)h * 64 + c8 * 8;
        *(float4*)op = v0;
        *(float4*)(op + 4) = v1;
    }
}

extern "C" void kernel_launch(void* const* d_in, const int* in_sizes, int n_in,
                              void* d_out, int out_size, void* d_ws, size_t ws_size,
                              hipStream_t stream) {
    const float* ego = (const float*)d_in[0];
    const float* rw  = (const float*)d_in[1];
    const int* eidx  = (const int*)d_in[2];
    const int* etyp  = (const int*)d_in[3];
    int N = in_sizes[0] / 64;
    int E = in_sizes[3];
    const int* head = eidx;
    const int* tail = eidx + E;
    float* out = (float*)d_out;

    char* ws = (char*)d_ws;
    size_t o = 0;
    auto take = [&](size_t bytes) -> char* {
        char* p = ws + o;
        o = (o + bytes + 255) & ~(size_t)255;
        return p;
    };
    int nb2 = (N + 511) / 512;
    int NB = (N + (1 << BSH) - 1) >> BSH;
    unsigned short* ego_bf = (unsigned short*)take((size_t)N * 64 * 2);
    short* wfrag    = (short*)take(16 * 4096 * 2);
    int* recs2      = (int*)take((size_t)E * 4);
    int2* staging   = (int2*)take((size_t)E * 8);
    int* headrank   = (int*)take((size_t)E * 4);
    int* head_cnt   = (int*)take((size_t)N * 4);
    int* head_off   = (int*)take((size_t)(N + 1) * 4);
    int* bucket_fill= (int*)take(NBMAX * 4);
    int* partial    = (int*)take((size_t)nb2 * 4);
    (void)ws_size; (void)n_in; (void)out_size;

    int NE8 = N * 8;
    k_init_bf<<<(NE8 + 255) / 256, 256, 0, stream>>>(ego, ego_bf, NE8,
                                                     head_cnt, N, rw, wfrag);
    k1_hist<<<(E + 255) / 256, 256, 0, stream>>>(head, E, head_cnt, headrank);
    k2a<<<nb2, 512, 0, stream>>>(head_cnt, N, partial);
    k2c<<<nb2, 512, 0, stream>>>(head_cnt, N, partial, head_off, bucket_fill, E);
    int nca = (E + CHUNKA - 1) / CHUNKA;
    k3a_bin<<<nca, 256, 0, stream>>>(head, tail, etyp, headrank, head_off, E,
                                     NB, bucket_fill, staging);
    int ncb = (E + 2047) / 2048;
    k3b_place<<<ncb, 256, 0, stream>>>(staging, E, recs2);
    k4_fused<<<(N + HPG - 1) / HPG, 512, 0, stream>>>(ego_bf, wfrag, recs2,
                                                      head_off, out, N);
}